// Round 3
// baseline (408.090 us; speedup 1.0000x reference)
//
#include <hip/hip_runtime.h>
#include <math.h>

#define BATCH 1024
#define SEQ   200
#define DIN   128
#define DOUT  128

typedef __attribute__((ext_vector_type(8))) short short8;
typedef __attribute__((ext_vector_type(4))) float f32x4;

// fp32 -> packed (bf16_hi << 16) | bf16_lo ; hi = round-half-up, lo = RTZ residual
// reconstruction hi+lo carries ~2^-17 relative error
__device__ __forceinline__ unsigned pack_split(float f) {
    unsigned u = __float_as_uint(f);
    unsigned r = u + 0x8000u;
    unsigned hi = r >> 16;
    float hf = __uint_as_float(r & 0xffff0000u);
    unsigned lo = __float_as_uint(f - hf) >> 16;
    return (hi << 16) | lo;
}

__device__ __forceinline__ void split2(float f, short& h, short& l) {
    unsigned u = __float_as_uint(f);
    unsigned r = u + 0x8000u;
    h = (short)(r >> 16);
    float hf = __uint_as_float(r & 0xffff0000u);
    l = (short)(__float_as_uint(f - hf) >> 16);
}

// ---- pre-split S into MFMA B-fragment order (hi at idx, lo at 16384+idx) ----
// idx = ((nt*4+kt)*64+lane)*8 + j ; element k = kt*32+(lane>>4)*8+j, n = nt*16+(lane&15)
__global__ __launch_bounds__(256) void k_presplit(const float* __restrict__ S,
                                                  short* __restrict__ Sp) {
    int g = blockIdx.x * 256 + threadIdx.x;          // 0..16383
    int j = g & 7, lane = (g >> 3) & 63, kt = (g >> 9) & 3, nt = g >> 11;
    int k = kt * 32 + (lane >> 4) * 8 + j;
    int n = nt * 16 + (lane & 15);
    short h, l;
    split2(S[k * DOUT + n], h, l);
    Sp[g] = h;
    Sp[16384 + g] = l;
}

// ---- K1: low_new = A @ S, output PACKED (bf16 hi|lo in u32) ----
// block = 256 thr = 4 waves; wave = 32 rows (mt 0/1) x 128 cols (nt 0..7)
__global__ __launch_bounds__(256, 2) void k_gemm(const float* __restrict__ A,
                                                 const short* __restrict__ Sp,
                                                 unsigned* __restrict__ outp) {
    const int t = threadIdx.x;
    const int w = t >> 6, lane = t & 63;
    const int q = lane >> 4, c = lane & 15;
    const long rowb = (long)blockIdx.x * 128 + w * 32;

    f32x4 acc[2][8];
    const f32x4 zz = {0.f, 0.f, 0.f, 0.f};
#pragma unroll
    for (int mt = 0; mt < 2; ++mt)
#pragma unroll
        for (int nt = 0; nt < 8; ++nt) acc[mt][nt] = zz;

#pragma unroll
    for (int kt = 0; kt < 4; ++kt) {
        short8 ah[2], al[2];
#pragma unroll
        for (int mt = 0; mt < 2; ++mt) {
            const float* ap = A + (rowb + mt * 16 + c) * DIN + kt * 32 + q * 8;
            float av[8];
            *(float4*)&av[0] = *(const float4*)ap;
            *(float4*)&av[4] = *(const float4*)(ap + 4);
#pragma unroll
            for (int j = 0; j < 8; ++j) {
                short h, l;
                split2(av[j], h, l);
                ah[mt][j] = h; al[mt][j] = l;
            }
        }
#pragma unroll
        for (int nt = 0; nt < 8; ++nt) {
            const short* fp = Sp + ((nt * 4 + kt) * 64 + lane) * 8;
            short8 sh = *(const short8*)fp;
            short8 sl = *(const short8*)(fp + 16384);
#pragma unroll
            for (int mt = 0; mt < 2; ++mt) {
                acc[mt][nt] = __builtin_amdgcn_mfma_f32_16x16x32_bf16(ah[mt], sh, acc[mt][nt], 0, 0, 0);
                acc[mt][nt] = __builtin_amdgcn_mfma_f32_16x16x32_bf16(al[mt], sh, acc[mt][nt], 0, 0, 0);
                acc[mt][nt] = __builtin_amdgcn_mfma_f32_16x16x32_bf16(ah[mt], sl, acc[mt][nt], 0, 0, 0);
            }
        }
    }
    // C/D: col = lane&15, row = (lane>>4)*4 + r
#pragma unroll
    for (int mt = 0; mt < 2; ++mt)
#pragma unroll
        for (int nt = 0; nt < 8; ++nt) {
            long r0 = rowb + mt * 16 + q * 4;
#pragma unroll
            for (int r = 0; r < 4; ++r)
                outp[(r0 + r) * DOUT + nt * 16 + c] = pack_split(acc[mt][nt][r]);
        }
}

// ---- K2: one routing iteration, MFMA for both einsums ----
// Pass B: high_pre[3][128] = W[3][224] x low[224][128]   (K = l, zero-padded)
// Pass C: delta[3][208]   = high[3][128] x lowT[128][208] (K = e)
__global__ __launch_bounds__(256, 4) void k_iter(
    const unsigned* __restrict__ lowp,   // [B][200][128] packed hi|lo
    const float* __restrict__ Bm,        // [3][200]
    const int* __restrict__ seq,         // [B]
    float* __restrict__ acc0, float* __restrict__ acc1,
    float* __restrict__ out, int iter) {
    __shared__ unsigned sW[224 * 17];    // sW[l][m], m = capsule (pad 17)
    __shared__ unsigned sH[128 * 17];    // sH[e][m]

    const int t = threadIdx.x;
    const int lane = t & 63, w = t >> 6;
    const int q = lane >> 4, c = lane & 15;
    const int b = blockIdx.x;
    const unsigned* lp = lowp + (size_t)b * (SEQ * DIN);
    const f32x4 zz = {0.f, 0.f, 0.f, 0.f};

    for (int i = t; i < 224 * 17; i += 256) sW[i] = 0u;
    for (int i = t; i < 128 * 17; i += 256) sH[i] = 0u;
    __syncthreads();

    // ---- Pass A: masked softmax (wave k handles capsule k), store packed ----
    const int n = seq[b];
    if (w < 3) {
        const int k = w;
        float vv[4], pv[4];
        float m = -INFINITY;
#pragma unroll
        for (int i = 0; i < 4; ++i) {
            int l = lane + 64 * i;
            float v = -INFINITY;
            if (l < SEQ && l < n) {
                v = Bm[k * SEQ + l];
                if (iter >= 1) v += acc0[k * SEQ + l];
                if (iter >= 2) v += acc1[k * SEQ + l];
            }
            vv[i] = v;
            m = fmaxf(m, v);
        }
        for (int off = 32; off; off >>= 1) m = fmaxf(m, __shfl_xor(m, off, 64));
        float s = 0.f;
#pragma unroll
        for (int i = 0; i < 4; ++i) {
            pv[i] = (vv[i] == -INFINITY) ? 0.f : expf(vv[i] - m);
            s += pv[i];
        }
        for (int off = 32; off; off >>= 1) s += __shfl_xor(s, off, 64);
        float rs = 1.f / s;
#pragma unroll
        for (int i = 0; i < 4; ++i) {
            int l = lane + 64 * i;
            if (l < SEQ) sW[l * 17 + k] = pack_split(pv[i] * rs);
        }
    }
    __syncthreads();

    // ---- Pass B: wave w owns e-tiles {2w, 2w+1} ----
    f32x4 accB[2];
    accB[0] = zz; accB[1] = zz;
#pragma unroll
    for (int kt = 0; kt < 7; ++kt) {
        short8 wh, wl;
#pragma unroll
        for (int j = 0; j < 8; ++j) {
            unsigned u = sW[(kt * 32 + q * 8 + j) * 17 + c];
            wh[j] = (short)(u >> 16);
            wl[j] = (short)(u & 0xffffu);
        }
#pragma unroll
        for (int nn = 0; nn < 2; ++nn) {
            const int nt = 2 * w + nn;
            short8 bh, bl;
#pragma unroll
            for (int j = 0; j < 8; ++j) {
                const int l = kt * 32 + q * 8 + j;
                unsigned u = (l < SEQ) ? lp[l * DIN + nt * 16 + c] : 0u;
                bh[j] = (short)(u >> 16);
                bl[j] = (short)(u & 0xffffu);
            }
            accB[nn] = __builtin_amdgcn_mfma_f32_16x16x32_bf16(wh, bh, accB[nn], 0, 0, 0);
            accB[nn] = __builtin_amdgcn_mfma_f32_16x16x32_bf16(wl, bh, accB[nn], 0, 0, 0);
            accB[nn] = __builtin_amdgcn_mfma_f32_16x16x32_bf16(wh, bl, accB[nn], 0, 0, 0);
        }
    }

    // ---- squash: capsules live in rows 0-2 = regs 0-2 of quad-0 lanes ----
    if (q == 0) {
#pragma unroll
        for (int nn = 0; nn < 2; ++nn) {
            float g0 = accB[nn][0], g1 = accB[nn][1], g2 = accB[nn][2];
            float sq = g0 * g0 + g1 * g1 + g2 * g2;
            float scale = sq / (1.f + sq) / sqrtf(sq + 1e-9f);
            g0 *= scale; g1 *= scale; g2 *= scale;
            const int e = (2 * w + nn) * 16 + c;
            if (iter == 2) {
                out[((size_t)b * 3 + 0) * DOUT + e] = g0;
                out[((size_t)b * 3 + 1) * DOUT + e] = g1;
                out[((size_t)b * 3 + 2) * DOUT + e] = g2;
            } else {
                sH[e * 17 + 0] = pack_split(g0);
                sH[e * 17 + 1] = pack_split(g1);
                sH[e * 17 + 2] = pack_split(g2);
            }
        }
    }
    if (iter == 2) return;   // uniform exit
    __syncthreads();

    // ---- Pass C: A-frags (high) held for all 4 kt, l-tiles round-robin ----
    short8 hh[4], hl[4];
#pragma unroll
    for (int kt = 0; kt < 4; ++kt)
#pragma unroll
        for (int j = 0; j < 8; ++j) {
            unsigned u = sH[(kt * 32 + q * 8 + j) * 17 + c];
            hh[kt][j] = (short)(u >> 16);
            hl[kt][j] = (short)(u & 0xffffu);
        }
    float* accN = (iter == 0) ? acc0 : acc1;
    const int ntc = (w == 0) ? 4 : 3;
    for (int i = 0; i < ntc; ++i) {
        const int nt = w + 4 * i;        // 13 tiles: w0:{0,4,8,12} w1:{1,5,9} ...
        const int l = nt * 16 + c;
        f32x4 a = zz;
#pragma unroll
        for (int kt = 0; kt < 4; ++kt) {
            short8 bh, bl;
#pragma unroll
            for (int j = 0; j < 8; ++j) {
                unsigned u = (l < SEQ) ? lp[l * DIN + kt * 32 + q * 8 + j] : 0u;
                bh[j] = (short)(u >> 16);
                bl[j] = (short)(u & 0xffffu);
            }
            a = __builtin_amdgcn_mfma_f32_16x16x32_bf16(hh[kt], bh, a, 0, 0, 0);
            a = __builtin_amdgcn_mfma_f32_16x16x32_bf16(hl[kt], bh, a, 0, 0, 0);
            a = __builtin_amdgcn_mfma_f32_16x16x32_bf16(hh[kt], bl, a, 0, 0, 0);
        }
        if (q == 0 && l < SEQ) {
            atomicAdd(&accN[0 * SEQ + l], a[0]);
            atomicAdd(&accN[1 * SEQ + l], a[1]);
            atomicAdd(&accN[2 * SEQ + l], a[2]);
        }
    }
}

extern "C" void kernel_launch(void* const* d_in, const int* in_sizes, int n_in,
                              void* d_out, int out_size, void* d_ws, size_t ws_size,
                              hipStream_t stream) {
    const float* low_capsule = (const float*)d_in[0];   // [1024][200][128]
    const float* B_matrix    = (const float*)d_in[1];   // [1][3][200]
    const float* S_matrix    = (const float*)d_in[2];   // [128][128]
    const int*   seq_len     = (const int*)d_in[3];     // [1024]
    float* out = (float*)d_out;                         // [1024][3][128]

    unsigned* lowp = (unsigned*)d_ws;                         // 26,214,400 u32
    short* Sp      = (short*)(lowp + (size_t)BATCH * SEQ * DOUT);  // 32768 shorts
    float* acc     = (float*)(Sp + 2 * 16384);                // acc0[600], acc1[600]

    hipMemsetAsync(acc, 0, 2 * 600 * sizeof(float), stream);

    k_presplit<<<64, 256, 0, stream>>>(S_matrix, Sp);
    k_gemm<<<(BATCH * SEQ) / 128, 256, 0, stream>>>(low_capsule, Sp, lowp);

    k_iter<<<BATCH, 256, 0, stream>>>(lowp, B_matrix, seq_len, acc, acc + 600, out, 0);
    k_iter<<<BATCH, 256, 0, stream>>>(lowp, B_matrix, seq_len, acc, acc + 600, out, 1);
    k_iter<<<BATCH, 256, 0, stream>>>(lowp, B_matrix, seq_len, acc, acc + 600, out, 2);
}

// Round 4
// 391.886 us; speedup vs baseline: 1.0413x; 1.0413x over previous
//
#include <hip/hip_runtime.h>
#include <math.h>

#define BATCH 1024
#define SEQ   200
#define DIN   128
#define DOUT  128
#define HALF  64
#define LSTR  68   // LDS row stride (u32) for k_iter: mult of 4 (b128 align), banks ~2-way

typedef __attribute__((ext_vector_type(8))) short short8;
typedef __attribute__((ext_vector_type(4))) float f32x4;

// fp32 -> packed (bf16_hi << 16) | bf16_lo ; hi = round-half-up, lo = RTZ residual
__device__ __forceinline__ unsigned pack_split(float f) {
    unsigned u = __float_as_uint(f);
    unsigned r = u + 0x8000u;
    unsigned hi = r >> 16;
    float hf = __uint_as_float(r & 0xffff0000u);
    unsigned lo = __float_as_uint(f - hf) >> 16;
    return (hi << 16) | lo;
}

__device__ __forceinline__ void split2(float f, short& h, short& l) {
    unsigned u = __float_as_uint(f);
    unsigned r = u + 0x8000u;
    h = (short)(r >> 16);
    float hf = __uint_as_float(r & 0xffff0000u);
    l = (short)(__float_as_uint(f - hf) >> 16);
}

// exact reconstruction of packed value
__device__ __forceinline__ float unpk(unsigned u) {
    return __uint_as_float(u & 0xffff0000u) + __uint_as_float(u << 16);
}

// ---- pre-split S into MFMA B-fragment order (hi at idx, lo at 16384+idx) ----
__global__ __launch_bounds__(256) void k_presplit(const float* __restrict__ S,
                                                  short* __restrict__ Sp) {
    int g = blockIdx.x * 256 + threadIdx.x;          // 0..16383
    int j = g & 7, lane = (g >> 3) & 63, kt = (g >> 9) & 3, nt = g >> 11;
    int k = kt * 32 + (lane >> 4) * 8 + j;
    int n = nt * 16 + (lane & 15);
    short h, l;
    split2(S[k * DOUT + n], h, l);
    Sp[g] = h;
    Sp[16384 + g] = l;
}

// ---- K1: low_new = A @ S, LDS-staged A tile, output packed u32 ----
// block = 128 rows, 256 thr; wave w: rows w*32..w*32+31, all 128 cols
__global__ __launch_bounds__(256, 2) void k_gemm(const float* __restrict__ A,
                                                 const short* __restrict__ Sp,
                                                 unsigned* __restrict__ outp) {
    __shared__ float sA[128 * 132];
    const int t = threadIdx.x;
    const int w = t >> 6, lane = t & 63;
    const int q = lane >> 4, c = lane & 15;
    const long row0 = (long)blockIdx.x * 128;
    const float* gp = A + row0 * DIN;

    // stage 128x128 fp32 tile, fully coalesced (1 KB per wave-inst)
#pragma unroll
    for (int i = 0; i < 16; ++i) {
        int flat = (t + 256 * i) * 4;
        int r = flat >> 7, col = flat & 127;
        float4 v = *(const float4*)(gp + flat);
        *(float4*)&sA[r * 132 + col] = v;
    }
    __syncthreads();

    f32x4 acc[2][8];
    const f32x4 zz = {0.f, 0.f, 0.f, 0.f};
#pragma unroll
    for (int mt = 0; mt < 2; ++mt)
#pragma unroll
        for (int nt = 0; nt < 8; ++nt) acc[mt][nt] = zz;

#pragma unroll
    for (int kt = 0; kt < 4; ++kt) {
        short8 ah[2], al[2];
#pragma unroll
        for (int mt = 0; mt < 2; ++mt) {
            const float* ap = &sA[(w * 32 + mt * 16 + c) * 132 + kt * 32 + q * 8];
            float av[8];
            *(float4*)&av[0] = *(const float4*)ap;
            *(float4*)&av[4] = *(const float4*)(ap + 4);
#pragma unroll
            for (int j = 0; j < 8; ++j) {
                short h, l;
                split2(av[j], h, l);
                ah[mt][j] = h; al[mt][j] = l;
            }
        }
#pragma unroll
        for (int nt = 0; nt < 8; ++nt) {
            const short* fp = Sp + ((nt * 4 + kt) * 64 + lane) * 8;
            short8 sh = *(const short8*)fp;
            short8 sl = *(const short8*)(fp + 16384);
#pragma unroll
            for (int mt = 0; mt < 2; ++mt) {
                acc[mt][nt] = __builtin_amdgcn_mfma_f32_16x16x32_bf16(ah[mt], sh, acc[mt][nt], 0, 0, 0);
                acc[mt][nt] = __builtin_amdgcn_mfma_f32_16x16x32_bf16(al[mt], sh, acc[mt][nt], 0, 0, 0);
                acc[mt][nt] = __builtin_amdgcn_mfma_f32_16x16x32_bf16(ah[mt], sl, acc[mt][nt], 0, 0, 0);
            }
        }
    }
    // C/D: col = lane&15, row = (lane>>4)*4 + r
#pragma unroll
    for (int mt = 0; mt < 2; ++mt)
#pragma unroll
        for (int nt = 0; nt < 8; ++nt) {
            long r0 = row0 + w * 32 + mt * 16 + q * 4;
#pragma unroll
            for (int r = 0; r < 4; ++r)
                outp[(r0 + r) * DOUT + nt * 16 + c] = pack_split(acc[mt][nt][r]);
        }
}

// ---- K2: one routing iteration; block = (batch, e-half); slice in LDS ----
__global__ __launch_bounds__(256, 2) void k_iter(
    const unsigned* __restrict__ lowp,   // [B][200][128] packed hi|lo
    const float* __restrict__ Bm,        // [3][200]
    const int* __restrict__ seq,         // [B]
    float* __restrict__ acc0, float* __restrict__ acc1,
    float* __restrict__ out, int iter) {
    __shared__ unsigned sLn[SEQ * LSTR];   // [l][e-half], 54.4 KB
    __shared__ float sW[SEQ * 4];          // [l][k], k<3 used
    __shared__ float sH[3 * HALF];         // [k][e]

    const int t = threadIdx.x;
    const int b = blockIdx.x >> 1;
    const int half = blockIdx.x & 1;
    const int lane = t & 63, w = t >> 6;
    const unsigned* lp = lowp + (size_t)b * (SEQ * DIN) + half * HALF;

    // ---- stage: 200 x 64 u32, contiguous uint4 loads ----
#pragma unroll
    for (int i = 0; i < 13; ++i) {
        int cc = t + 256 * i;
        if (cc < 3200) {
            int l = cc >> 4, e4 = (cc & 15) << 2;
            uint4 v = *(const uint4*)(lp + l * DIN + e4);
            *(uint4*)&sLn[l * LSTR + e4] = v;
        }
    }

    // ---- Pass A: masked softmax (wave k = capsule k), independent of sLn ----
    const int n = seq[b];
    if (w < 3) {
        const int k = w;
        float vv[4];
        float m = -INFINITY;
#pragma unroll
        for (int i = 0; i < 4; ++i) {
            int l = lane + 64 * i;
            float v = -INFINITY;
            if (l < SEQ && l < n) {
                v = Bm[k * SEQ + l];
                if (iter >= 1) v += acc0[k * SEQ + l];
                if (iter >= 2) v += acc1[k * SEQ + l];
            }
            vv[i] = v;
            m = fmaxf(m, v);
        }
        for (int off = 32; off; off >>= 1) m = fmaxf(m, __shfl_xor(m, off, 64));
        float s = 0.f, pv[4];
#pragma unroll
        for (int i = 0; i < 4; ++i) {
            pv[i] = (vv[i] == -INFINITY) ? 0.f : expf(vv[i] - m);
            s += pv[i];
        }
        for (int off = 32; off; off >>= 1) s += __shfl_xor(s, off, 64);
        float rs = 1.f / s;
#pragma unroll
        for (int i = 0; i < 4; ++i) {
            int l = lane + 64 * i;
            if (l < SEQ) sW[l * 4 + k] = pv[i] * rs;
        }
    }
    __syncthreads();

    // ---- Pass B: h[k][e] = sum_l W[k][l]*Ln[l][e]; thread = (e, lgroup) ----
    const int e = t >> 2, lg = t & 3;   // lg lives in lane bits 0..1
    float h0 = 0.f, h1 = 0.f, h2 = 0.f;
#pragma unroll 5
    for (int i = 0; i < 50; ++i) {
        int l = lg * 50 + i;
        float4 wv = *(const float4*)&sW[l * 4];     // 4-addr multicast, bank-disjoint
        float f = unpk(sLn[l * LSTR + e]);
        h0 = fmaf(wv.x, f, h0);
        h1 = fmaf(wv.y, f, h1);
        h2 = fmaf(wv.z, f, h2);
    }
    h0 += __shfl_xor(h0, 1, 64); h0 += __shfl_xor(h0, 2, 64);
    h1 += __shfl_xor(h1, 1, 64); h1 += __shfl_xor(h1, 2, 64);
    h2 += __shfl_xor(h2, 1, 64); h2 += __shfl_xor(h2, 2, 64);
    if ((t & 3) == 0) {
        float sq = h0 * h0 + h1 * h1 + h2 * h2;
        float scale = sq / (1.f + sq) / sqrtf(sq + 1e-9f);
        h0 *= scale; h1 *= scale; h2 *= scale;
        if (iter == 2) {
            size_t o = (size_t)b * 3 * DOUT + half * HALF + e;
            out[o] = h0; out[o + DOUT] = h1; out[o + 2 * DOUT] = h2;
        } else {
            sH[e] = h0; sH[HALF + e] = h1; sH[2 * HALF + e] = h2;
        }
    }
    if (iter == 2) return;   // uniform exit
    __syncthreads();

    // ---- Pass C: d[k][l] = sum_e h[k][e]*Ln[l][e]; thread = l ----
    const int l = (t < SEQ) ? t : 0;
    float d0 = 0.f, d1 = 0.f, d2 = 0.f;
#pragma unroll
    for (int j = 0; j < 16; ++j) {
        uint4 u = *(const uint4*)&sLn[l * LSTR + 4 * j];
        float4 a0 = *(const float4*)&sH[4 * j];             // broadcast
        float4 a1 = *(const float4*)&sH[HALF + 4 * j];
        float4 a2 = *(const float4*)&sH[2 * HALF + 4 * j];
        float f0 = unpk(u.x), f1 = unpk(u.y), f2 = unpk(u.z), f3 = unpk(u.w);
        d0 += a0.x * f0 + a0.y * f1 + a0.z * f2 + a0.w * f3;
        d1 += a1.x * f0 + a1.y * f1 + a1.z * f2 + a1.w * f3;
        d2 += a2.x * f0 + a2.y * f1 + a2.z * f2 + a2.w * f3;
    }
    if (t < SEQ) {
        float* accN = (iter == 0) ? acc0 : acc1;
        atomicAdd(&accN[l], d0);
        atomicAdd(&accN[SEQ + l], d1);
        atomicAdd(&accN[2 * SEQ + l], d2);
    }
}

extern "C" void kernel_launch(void* const* d_in, const int* in_sizes, int n_in,
                              void* d_out, int out_size, void* d_ws, size_t ws_size,
                              hipStream_t stream) {
    const float* low_capsule = (const float*)d_in[0];   // [1024][200][128]
    const float* B_matrix    = (const float*)d_in[1];   // [1][3][200]
    const float* S_matrix    = (const float*)d_in[2];   // [128][128]
    const int*   seq_len     = (const int*)d_in[3];     // [1024]
    float* out = (float*)d_out;                         // [1024][3][128]

    unsigned* lowp = (unsigned*)d_ws;                               // 26,214,400 u32
    short* Sp      = (short*)(lowp + (size_t)BATCH * SEQ * DOUT);   // 32768 shorts
    float* acc     = (float*)(Sp + 2 * 16384);                      // acc0[600], acc1[600]

    hipMemsetAsync(acc, 0, 2 * 600 * sizeof(float), stream);

    k_presplit<<<64, 256, 0, stream>>>(S_matrix, Sp);
    k_gemm<<<(BATCH * SEQ) / 128, 256, 0, stream>>>(low_capsule, Sp, lowp);

    k_iter<<<2 * BATCH, 256, 0, stream>>>(lowp, B_matrix, seq_len, acc, acc + 600, out, 0);
    k_iter<<<2 * BATCH, 256, 0, stream>>>(lowp, B_matrix, seq_len, acc, acc + 600, out, 1);
    k_iter<<<2 * BATCH, 256, 0, stream>>>(lowp, B_matrix, seq_len, acc, acc + 600, out, 2);
}

// Round 5
// 310.363 us; speedup vs baseline: 1.3149x; 1.2627x over previous
//
#include <hip/hip_runtime.h>
#include <math.h>

#define BATCH 1024
#define SEQ   200
#define DIN   128
#define DOUT  128
#define HALF  64
#define LSTR  68     // k_iter LDS row stride (u32): mult of 4, ~2-way banks (free)
#define PSTR  608    // partial-delta row stride (floats): 600 data + 8 pad

typedef __attribute__((ext_vector_type(8))) short short8;
typedef __attribute__((ext_vector_type(4))) float f32x4;

// fp32 -> packed (bf16_hi << 16) | bf16_lo ; hi = round-half-up, lo = RTZ residual
__device__ __forceinline__ unsigned pack_split(float f) {
    unsigned u = __float_as_uint(f);
    unsigned r = u + 0x8000u;
    unsigned hi = r >> 16;
    float hf = __uint_as_float(r & 0xffff0000u);
    unsigned lo = __float_as_uint(f - hf) >> 16;
    return (hi << 16) | lo;
}

__device__ __forceinline__ void split2(float f, short& h, short& l) {
    unsigned u = __float_as_uint(f);
    unsigned r = u + 0x8000u;
    h = (short)(r >> 16);
    float hf = __uint_as_float(r & 0xffff0000u);
    l = (short)(__float_as_uint(f - hf) >> 16);
}

// exact reconstruction of packed value
__device__ __forceinline__ float unpk(unsigned u) {
    return __uint_as_float(u & 0xffff0000u) + __uint_as_float(u << 16);
}

// ---- pre-split S into MFMA B-fragment order (hi at idx, lo at 16384+idx) ----
// idx = ((nt*4+kt)*64+lane)*8 + j ; element k = kt*32+(lane>>4)*8+j, n = nt*16+(lane&15)
__global__ __launch_bounds__(256) void k_presplit(const float* __restrict__ S,
                                                  short* __restrict__ Sp) {
    int g = blockIdx.x * 256 + threadIdx.x;          // 0..16383
    int j = g & 7, lane = (g >> 3) & 63, kt = (g >> 9) & 3, nt = g >> 11;
    int k = kt * 32 + (lane >> 4) * 8 + j;
    int n = nt * 16 + (lane & 15);
    short h, l;
    split2(S[k * DOUT + n], h, l);
    Sp[g] = h;
    Sp[16384 + g] = l;
}

// ---- K1: low_new = A @ S ; Sp resident in LDS, A streamed global->reg ----
// block = 128 rows, 256 thr; wave w: rows w*32..w*32+31 (mt 0/1), all 128 cols
__global__ __launch_bounds__(256, 2) void k_gemm(const float* __restrict__ A,
                                                 const short* __restrict__ Sp,
                                                 unsigned* __restrict__ outp) {
    __shared__ short sSp[32768];   // 64 KB: hi [0..16383], lo [16384..]
    const int t = threadIdx.x;
    const int w = t >> 6, lane = t & 63;
    const int q = lane >> 4, c = lane & 15;
    const long rowb = (long)blockIdx.x * 128 + w * 32;

    // stage full Sp (fragment-ordered), coalesced uint4
#pragma unroll
    for (int i = 0; i < 16; ++i)
        *(uint4*)&sSp[(t + 256 * i) * 8] = *(const uint4*)&Sp[(t + 256 * i) * 8];
    __syncthreads();   // only barrier; sSp is read-only afterwards

    f32x4 acc[2][8];
    const f32x4 zz = {0.f, 0.f, 0.f, 0.f};
#pragma unroll
    for (int mt = 0; mt < 2; ++mt)
#pragma unroll
        for (int nt = 0; nt < 8; ++nt) acc[mt][nt] = zz;

#pragma unroll
    for (int kt = 0; kt < 4; ++kt) {
        short8 ah[2], al[2];
#pragma unroll
        for (int mt = 0; mt < 2; ++mt) {
            // wave covers 16 rows x contiguous 128B per inst — fully coalesced
            const float* ap = A + (rowb + mt * 16 + c) * DIN + kt * 32 + q * 8;
            float av[8];
            *(float4*)&av[0] = *(const float4*)ap;
            *(float4*)&av[4] = *(const float4*)(ap + 4);
#pragma unroll
            for (int j = 0; j < 8; ++j) {
                short h, l;
                split2(av[j], h, l);
                ah[mt][j] = h; al[mt][j] = l;
            }
        }
#pragma unroll
        for (int nt = 0; nt < 8; ++nt) {
            const int fo = ((nt * 4 + kt) * 64 + lane) * 8;   // 16B/lane contiguous
            short8 sh = *(const short8*)&sSp[fo];
            short8 sl = *(const short8*)&sSp[16384 + fo];
#pragma unroll
            for (int mt = 0; mt < 2; ++mt) {
                acc[mt][nt] = __builtin_amdgcn_mfma_f32_16x16x32_bf16(ah[mt], sh, acc[mt][nt], 0, 0, 0);
                acc[mt][nt] = __builtin_amdgcn_mfma_f32_16x16x32_bf16(al[mt], sh, acc[mt][nt], 0, 0, 0);
                acc[mt][nt] = __builtin_amdgcn_mfma_f32_16x16x32_bf16(ah[mt], sl, acc[mt][nt], 0, 0, 0);
            }
        }
    }
    // C/D: col = lane&15, row = (lane>>4)*4 + r
#pragma unroll
    for (int mt = 0; mt < 2; ++mt)
#pragma unroll
        for (int nt = 0; nt < 8; ++nt) {
            long r0 = rowb + mt * 16 + q * 4;
#pragma unroll
            for (int r = 0; r < 4; ++r)
                outp[(r0 + r) * DOUT + nt * 16 + c] = pack_split(acc[mt][nt][r]);
        }
}

// ---- K2: one routing iteration; block = (batch, e-half); NO atomics ----
__global__ __launch_bounds__(256, 2) void k_iter(
    const unsigned* __restrict__ lowp,   // [B][200][128] packed hi|lo
    const float* __restrict__ Bm,        // [3][200]
    const int* __restrict__ seq,         // [B]
    const float* __restrict__ acc0, const float* __restrict__ acc1,
    float* __restrict__ part,            // [2048][PSTR] per-block partial deltas
    float* __restrict__ out, int iter) {
    __shared__ unsigned sLn[SEQ * LSTR];   // [l][e-half], 54.4 KB
    __shared__ float sW[SEQ * 4];          // [l][k], k<3 used
    __shared__ float sH[3 * HALF];         // [k][e]

    const int t = threadIdx.x;
    const int b = blockIdx.x >> 1;
    const int half = blockIdx.x & 1;
    const int lane = t & 63, w = t >> 6;
    const unsigned* lp = lowp + (size_t)b * (SEQ * DIN) + half * HALF;

    // ---- stage: 200 x 64 u32, contiguous uint4 loads ----
#pragma unroll
    for (int i = 0; i < 13; ++i) {
        int cc = t + 256 * i;
        if (cc < 3200) {
            int l = cc >> 4, e4 = (cc & 15) << 2;
            uint4 v = *(const uint4*)(lp + l * DIN + e4);
            *(uint4*)&sLn[l * LSTR + e4] = v;
        }
    }

    // ---- Pass A: masked softmax (wave k = capsule k), independent of sLn ----
    const int n = seq[b];
    if (w < 3) {
        const int k = w;
        float vv[4];
        float m = -INFINITY;
#pragma unroll
        for (int i = 0; i < 4; ++i) {
            int l = lane + 64 * i;
            float v = -INFINITY;
            if (l < SEQ && l < n) {
                v = Bm[k * SEQ + l];
                if (iter >= 1) v += acc0[k * SEQ + l];
                if (iter >= 2) v += acc1[k * SEQ + l];
            }
            vv[i] = v;
            m = fmaxf(m, v);
        }
        for (int off = 32; off; off >>= 1) m = fmaxf(m, __shfl_xor(m, off, 64));
        float s = 0.f, pv[4];
#pragma unroll
        for (int i = 0; i < 4; ++i) {
            pv[i] = (vv[i] == -INFINITY) ? 0.f : expf(vv[i] - m);
            s += pv[i];
        }
        for (int off = 32; off; off >>= 1) s += __shfl_xor(s, off, 64);
        float rs = 1.f / s;
#pragma unroll
        for (int i = 0; i < 4; ++i) {
            int l = lane + 64 * i;
            if (l < SEQ) sW[l * 4 + k] = pv[i] * rs;
        }
    }
    __syncthreads();

    // ---- Pass B: h[k][e] = sum_l W[k][l]*Ln[l][e]; thread = (e, lgroup) ----
    const int e = t >> 2, lg = t & 3;   // lg lives in lane bits 0..1
    float h0 = 0.f, h1 = 0.f, h2 = 0.f;
#pragma unroll 5
    for (int i = 0; i < 50; ++i) {
        int l = lg * 50 + i;
        float4 wv = *(const float4*)&sW[l * 4];     // 4-addr multicast
        float f = unpk(sLn[l * LSTR + e]);
        h0 = fmaf(wv.x, f, h0);
        h1 = fmaf(wv.y, f, h1);
        h2 = fmaf(wv.z, f, h2);
    }
    h0 += __shfl_xor(h0, 1, 64); h0 += __shfl_xor(h0, 2, 64);
    h1 += __shfl_xor(h1, 1, 64); h1 += __shfl_xor(h1, 2, 64);
    h2 += __shfl_xor(h2, 1, 64); h2 += __shfl_xor(h2, 2, 64);
    if ((t & 3) == 0) {
        float sq = h0 * h0 + h1 * h1 + h2 * h2;
        float scale = sq / (1.f + sq) / sqrtf(sq + 1e-9f);
        h0 *= scale; h1 *= scale; h2 *= scale;
        if (iter == 2) {
            size_t o = (size_t)b * 3 * DOUT + half * HALF + e;
            out[o] = h0; out[o + DOUT] = h1; out[o + 2 * DOUT] = h2;
        } else {
            sH[e] = h0; sH[HALF + e] = h1; sH[2 * HALF + e] = h2;
        }
    }
    if (iter == 2) return;   // uniform exit
    __syncthreads();

    // ---- Pass C: d[k][l] = sum_e h[k][e]*Ln[l][e]; thread = l ----
    const int l = (t < SEQ) ? t : 0;
    float d0 = 0.f, d1 = 0.f, d2 = 0.f;
#pragma unroll
    for (int j = 0; j < 16; ++j) {
        uint4 u = *(const uint4*)&sLn[l * LSTR + 4 * j];
        float4 a0 = *(const float4*)&sH[4 * j];             // broadcast
        float4 a1 = *(const float4*)&sH[HALF + 4 * j];
        float4 a2 = *(const float4*)&sH[2 * HALF + 4 * j];
        float f0 = unpk(u.x), f1 = unpk(u.y), f2 = unpk(u.z), f3 = unpk(u.w);
        d0 += a0.x * f0 + a0.y * f1 + a0.z * f2 + a0.w * f3;
        d1 += a1.x * f0 + a1.y * f1 + a1.z * f2 + a1.w * f3;
        d2 += a2.x * f0 + a2.y * f1 + a2.z * f2 + a2.w * f3;
    }
    if (t < SEQ) {
        float* pp = part + (size_t)blockIdx.x * PSTR;
        pp[l] = d0;                // plain stores — contention-free
        pp[SEQ + l] = d1;
        pp[2 * SEQ + l] = d2;
    }
}

// ---- K3: column-sum part[2048][PSTR] -> accN[600] ----
// grid 38 blocks x 256 thr; thread (rg = t>>4, c = t&15), block owns 16 cols
__global__ __launch_bounds__(256) void k_reduce(const float* __restrict__ part,
                                                float* __restrict__ accN) {
    __shared__ float sR[16][17];
    const int t = threadIdx.x;
    const int rg = t >> 4, c = t & 15;
    const int col = blockIdx.x * 16 + c;
    float s = 0.f;
#pragma unroll 8
    for (int r = rg; r < 2048; r += 16)
        s += part[(size_t)r * PSTR + col];   // 64B-line coalesced per 16 lanes
    sR[rg][c] = s;
    __syncthreads();
    if (rg == 0) {
        float tot = 0.f;
#pragma unroll
        for (int i = 0; i < 16; ++i) tot += sR[i][c];
        if (col < 600) accN[col] = tot;
    }
}

extern "C" void kernel_launch(void* const* d_in, const int* in_sizes, int n_in,
                              void* d_out, int out_size, void* d_ws, size_t ws_size,
                              hipStream_t stream) {
    const float* low_capsule = (const float*)d_in[0];   // [1024][200][128]
    const float* B_matrix    = (const float*)d_in[1];   // [1][3][200]
    const float* S_matrix    = (const float*)d_in[2];   // [128][128]
    const int*   seq_len     = (const int*)d_in[3];     // [1024]
    float* out = (float*)d_out;                         // [1024][3][128]

    unsigned* lowp = (unsigned*)d_ws;                              // 26,214,400 u32
    short* Sp      = (short*)(lowp + (size_t)BATCH * SEQ * DOUT);  // 32768 shorts
    float* acc0    = (float*)(Sp + 32768);                         // 600
    float* acc1    = acc0 + 640;                                   // 600 (pad 640)
    float* part    = acc1 + 640;                                   // 2048 * PSTR

    k_presplit<<<64, 256, 0, stream>>>(S_matrix, Sp);
    k_gemm<<<(BATCH * SEQ) / 128, 256, 0, stream>>>(low_capsule, Sp, lowp);

    k_iter<<<2 * BATCH, 256, 0, stream>>>(lowp, B_matrix, seq_len, acc0, acc1, part, out, 0);
    k_reduce<<<38, 256, 0, stream>>>(part, acc0);
    k_iter<<<2 * BATCH, 256, 0, stream>>>(lowp, B_matrix, seq_len, acc0, acc1, part, out, 1);
    k_reduce<<<38, 256, 0, stream>>>(part, acc1);
    k_iter<<<2 * BATCH, 256, 0, stream>>>(lowp, B_matrix, seq_len, acc0, acc1, part, out, 2);
}

// Round 6
// 284.837 us; speedup vs baseline: 1.4327x; 1.0896x over previous
//
#include <hip/hip_runtime.h>
#include <math.h>

#define BATCH 1024
#define SEQ   200
#define DIN   128
#define DOUT  128
#define HALF  64
#define PSTR  608    // partial-delta row stride (floats): 600 data + 8 pad

typedef __attribute__((ext_vector_type(8))) short short8;
typedef __attribute__((ext_vector_type(4))) float f32x4;

// async global->LDS, 16B per lane; LDS dest = wave-uniform base + lane*16
__device__ __forceinline__ void async_copy16(const void* g, void* l) {
    __builtin_amdgcn_global_load_lds((const __attribute__((address_space(1))) void*)g,
                                     (__attribute__((address_space(3))) void*)l,
                                     16, 0, 0);
}

// fp32 -> packed (bf16_hi << 16) | bf16_lo ; hi = round-half-up, lo = RTZ residual
__device__ __forceinline__ unsigned pack_split(float f) {
    unsigned u = __float_as_uint(f);
    unsigned r = u + 0x8000u;
    unsigned hi = r >> 16;
    float hf = __uint_as_float(r & 0xffff0000u);
    unsigned lo = __float_as_uint(f - hf) >> 16;
    return (hi << 16) | lo;
}

__device__ __forceinline__ void split2(float f, short& h, short& l) {
    unsigned u = __float_as_uint(f);
    unsigned r = u + 0x8000u;
    h = (short)(r >> 16);
    float hf = __uint_as_float(r & 0xffff0000u);
    l = (short)(__float_as_uint(f - hf) >> 16);
}

// exact reconstruction of packed value
__device__ __forceinline__ float unpk(unsigned u) {
    return __uint_as_float(u & 0xffff0000u) + __uint_as_float(u << 16);
}

// ---- pre-split S into MFMA B-fragment order (hi at idx, lo at 16384+idx) ----
__global__ __launch_bounds__(256) void k_presplit(const float* __restrict__ S,
                                                  short* __restrict__ Sp) {
    int g = blockIdx.x * 256 + threadIdx.x;          // 0..16383
    int j = g & 7, lane = (g >> 3) & 63, kt = (g >> 9) & 3, nt = g >> 11;
    int k = kt * 32 + (lane >> 4) * 8 + j;
    int n = nt * 16 + (lane & 15);
    short h, l;
    split2(S[k * DOUT + n], h, l);
    Sp[g] = h;
    Sp[16384 + g] = l;
}

// ---- K1: low_new = A @ S ; A loads all-upfront, Sp async->LDS ----
__global__ __launch_bounds__(256, 2) void k_gemm(const float* __restrict__ A,
                                                 const short* __restrict__ Sp,
                                                 unsigned* __restrict__ outp) {
    __shared__ short sSp[32768];   // 64 KB: hi [0..16383], lo [16384..]
    const int t = threadIdx.x;
    const int w = t >> 6, lane = t & 63;
    const int q = lane >> 4, c = lane & 15;
    const long rowb = (long)blockIdx.x * 128 + w * 32;

    // (1) all 16 A-loads issued first (oldest in vmcnt order)
    float4 araw[4][2][2];
#pragma unroll
    for (int kt = 0; kt < 4; ++kt)
#pragma unroll
        for (int mt = 0; mt < 2; ++mt) {
            const float* ap = A + (rowb + mt * 16 + c) * DIN + kt * 32 + q * 8;
            araw[kt][mt][0] = *(const float4*)ap;
            araw[kt][mt][1] = *(const float4*)(ap + 4);
        }

    // (2) async Sp stage: 16 x 1KB per wave, no VGPR round trip
#pragma unroll
    for (int i = 0; i < 16; ++i) {
        const int g = w * 16 + i;
        async_copy16(Sp + g * 512 + lane * 8, &sSp[g * 512]);
    }

    // (3) split A (waits only on A loads — they retire first)
    short8 ah[4][2], al[4][2];
#pragma unroll
    for (int kt = 0; kt < 4; ++kt)
#pragma unroll
        for (int mt = 0; mt < 2; ++mt) {
            float av[8];
            *(float4*)&av[0] = araw[kt][mt][0];
            *(float4*)&av[4] = araw[kt][mt][1];
#pragma unroll
            for (int j = 0; j < 8; ++j) {
                short h, l;
                split2(av[j], h, l);
                ah[kt][mt][j] = h; al[kt][mt][j] = l;
            }
        }

    f32x4 acc[2][8];
    const f32x4 zz = {0.f, 0.f, 0.f, 0.f};
#pragma unroll
    for (int mt = 0; mt < 2; ++mt)
#pragma unroll
        for (int nt = 0; nt < 8; ++nt) acc[mt][nt] = zz;

    __syncthreads();   // drains async Sp stage

    // (4) MFMA loop: LDS b128 reads (lane-contiguous, conflict-free)
#pragma unroll
    for (int kt = 0; kt < 4; ++kt)
#pragma unroll
        for (int nt = 0; nt < 8; ++nt) {
            const int fo = ((nt * 4 + kt) * 64 + lane) * 8;
            short8 sh = *(const short8*)&sSp[fo];
            short8 sl = *(const short8*)&sSp[16384 + fo];
#pragma unroll
            for (int mt = 0; mt < 2; ++mt) {
                acc[mt][nt] = __builtin_amdgcn_mfma_f32_16x16x32_bf16(ah[kt][mt], sh, acc[mt][nt], 0, 0, 0);
                acc[mt][nt] = __builtin_amdgcn_mfma_f32_16x16x32_bf16(al[kt][mt], sh, acc[mt][nt], 0, 0, 0);
                acc[mt][nt] = __builtin_amdgcn_mfma_f32_16x16x32_bf16(ah[kt][mt], sl, acc[mt][nt], 0, 0, 0);
            }
        }
    // C/D: col = lane&15, row = (lane>>4)*4 + r
#pragma unroll
    for (int mt = 0; mt < 2; ++mt)
#pragma unroll
        for (int nt = 0; nt < 8; ++nt) {
            long r0 = rowb + mt * 16 + q * 4;
#pragma unroll
            for (int r = 0; r < 4; ++r)
                outp[(r0 + r) * DOUT + nt * 16 + c] = pack_split(acc[mt][nt][r]);
        }
}

// ---- K2: one routing iteration; async stage, block = (batch, e-half) ----
__global__ __launch_bounds__(256, 2) void k_iter(
    const unsigned* __restrict__ lowp,   // [B][200][128] packed hi|lo
    const float* __restrict__ Bm,        // [3][200]
    const int* __restrict__ seq,         // [B]
    const float* __restrict__ acc0, const float* __restrict__ acc1,
    float* __restrict__ part,            // [2048][PSTR]
    float* __restrict__ out, int iter) {
    __shared__ unsigned sLn[SEQ * HALF];   // [l][e], 51.2 KB, NO pad (async dest)
    __shared__ float sW[SEQ * 4];          // [l][k], k<3 used
    __shared__ float pB[4][3][HALF];       // per-wave Pass-B partials
    __shared__ float sH[3][HALF];

    const int t = threadIdx.x;
    const int lane = t & 63, w = t >> 6;
    const int b = blockIdx.x >> 1, half = blockIdx.x & 1;
    const unsigned* lp = lowp + (size_t)b * (SEQ * DIN) + half * HALF;
    const int n = seq[b];

    // (1) softmax raw loads FIRST (retire before the async stream)
    float a0v[4], a1v[4], a2v[4];
    if (w < 3) {
        const int k = w;
#pragma unroll
        for (int i = 0; i < 4; ++i) {
            int l = lane + 64 * i;
            bool inb = (l < SEQ);
            a0v[i] = inb ? Bm[k * SEQ + l] : 0.f;
            a1v[i] = (inb && iter >= 1) ? acc0[k * SEQ + l] : 0.f;
            a2v[i] = (inb && iter >= 2) ? acc1[k * SEQ + l] : 0.f;
        }
    }

    // (2) async stage: 50 x 1KB wave-insts (4 rows each), linear [l][64] layout
    for (int g = w; g < 50; g += 4)
        async_copy16(lp + (g * 4 + (lane >> 4)) * DIN + (lane & 15) * 4,
                     &sLn[g * 256]);

    // (3) softmax compute
    if (w < 3) {
        const int k = w;
        float vv[4], m = -INFINITY;
#pragma unroll
        for (int i = 0; i < 4; ++i) {
            int l = lane + 64 * i;
            float v = a0v[i] + a1v[i] + a2v[i];
            vv[i] = (l < n) ? v : -INFINITY;   // l<n implies l<SEQ
            if (l < n) m = fmaxf(m, v);
        }
        for (int off = 32; off; off >>= 1) m = fmaxf(m, __shfl_xor(m, off, 64));
        float s = 0.f, pv[4];
#pragma unroll
        for (int i = 0; i < 4; ++i) {
            pv[i] = (vv[i] == -INFINITY) ? 0.f : expf(vv[i] - m);
            s += pv[i];
        }
        for (int off = 32; off; off >>= 1) s += __shfl_xor(s, off, 64);
        float rs = 1.f / s;
#pragma unroll
        for (int i = 0; i < 4; ++i) {
            int l = lane + 64 * i;
            if (l < SEQ) sW[l * 4 + k] = pv[i] * rs;
        }
    }
    __syncthreads();   // single vmcnt drain for the whole stage

    // (4) Pass B: wave w sums l in [50w, 50w+50); lane = e (2-way banks, free)
    {
        const int e = lane;
        float h0 = 0.f, h1 = 0.f, h2 = 0.f;
        for (int i = 0; i < 50; ++i) {
            int l = w * 50 + i;
            float4 wv = *(const float4*)&sW[l * 4];   // wave-uniform broadcast
            float f = unpk(sLn[l * 64 + e]);
            h0 = fmaf(wv.x, f, h0);
            h1 = fmaf(wv.y, f, h1);
            h2 = fmaf(wv.z, f, h2);
        }
        pB[w][0][e] = h0; pB[w][1][e] = h1; pB[w][2][e] = h2;
    }
    __syncthreads();

    // (5) cross-wave reduce + squash (single wave)
    if (t < HALF) {
        float g0 = pB[0][0][t] + pB[1][0][t] + pB[2][0][t] + pB[3][0][t];
        float g1 = pB[0][1][t] + pB[1][1][t] + pB[2][1][t] + pB[3][1][t];
        float g2 = pB[0][2][t] + pB[1][2][t] + pB[2][2][t] + pB[3][2][t];
        float sq = g0 * g0 + g1 * g1 + g2 * g2;
        float scale = sq / (1.f + sq) / sqrtf(sq + 1e-9f);
        g0 *= scale; g1 *= scale; g2 *= scale;
        if (iter == 2) {
            size_t o = (size_t)b * 3 * DOUT + half * HALF + t;
            out[o] = g0; out[o + DOUT] = g1; out[o + 2 * DOUT] = g2;
        } else {
            sH[0][t] = g0; sH[1][t] = g1; sH[2][t] = g2;
        }
    }
    if (iter == 2) return;   // uniform exit
    __syncthreads();

    // (6) Pass C: thread = l; chunk order rotated per lane -> conflict-free
    if (t < SEQ) {
        const int l = t;
        float d0 = 0.f, d1 = 0.f, d2 = 0.f;
#pragma unroll
        for (int j = 0; j < 16; ++j) {
            const int jj = (j + l) & 15;
            uint4 u = *(const uint4*)&sLn[l * 64 + 4 * jj];
            float4 x0 = *(const float4*)&sH[0][4 * jj];
            float4 x1 = *(const float4*)&sH[1][4 * jj];
            float4 x2 = *(const float4*)&sH[2][4 * jj];
            float f0 = unpk(u.x), f1 = unpk(u.y), f2 = unpk(u.z), f3 = unpk(u.w);
            d0 += x0.x * f0 + x0.y * f1 + x0.z * f2 + x0.w * f3;
            d1 += x1.x * f0 + x1.y * f1 + x1.z * f2 + x1.w * f3;
            d2 += x2.x * f0 + x2.y * f1 + x2.z * f2 + x2.w * f3;
        }
        float* pp = part + (size_t)blockIdx.x * PSTR;
        pp[l] = d0;
        pp[SEQ + l] = d1;
        pp[2 * SEQ + l] = d2;
    }
}

// ---- K3: column-sum part[2048][PSTR] -> accN[600]; 150 blocks x 4 cols ----
__global__ __launch_bounds__(256) void k_reduce(const float* __restrict__ part,
                                                float* __restrict__ accN) {
    __shared__ float sP[4][4];
    const int t = threadIdx.x, lane = t & 63, w = t >> 6;
    const int c4 = blockIdx.x * 4;
    float sx = 0.f, sy = 0.f, sz = 0.f, sw = 0.f;
#pragma unroll
    for (int i = 0; i < 8; ++i) {
        float4 v = *(const float4*)&part[(size_t)(t + 256 * i) * PSTR + c4];
        sx += v.x; sy += v.y; sz += v.z; sw += v.w;
    }
#pragma unroll
    for (int off = 1; off < 64; off <<= 1) {
        sx += __shfl_xor(sx, off, 64);
        sy += __shfl_xor(sy, off, 64);
        sz += __shfl_xor(sz, off, 64);
        sw += __shfl_xor(sw, off, 64);
    }
    if (lane == 0) { sP[w][0] = sx; sP[w][1] = sy; sP[w][2] = sz; sP[w][3] = sw; }
    __syncthreads();
    if (t < 4)
        accN[c4 + t] = sP[0][t] + sP[1][t] + sP[2][t] + sP[3][t];
}

extern "C" void kernel_launch(void* const* d_in, const int* in_sizes, int n_in,
                              void* d_out, int out_size, void* d_ws, size_t ws_size,
                              hipStream_t stream) {
    const float* low_capsule = (const float*)d_in[0];   // [1024][200][128]
    const float* B_matrix    = (const float*)d_in[1];   // [1][3][200]
    const float* S_matrix    = (const float*)d_in[2];   // [128][128]
    const int*   seq_len     = (const int*)d_in[3];     // [1024]
    float* out = (float*)d_out;                         // [1024][3][128]

    unsigned* lowp = (unsigned*)d_ws;                              // 26,214,400 u32
    short* Sp      = (short*)(lowp + (size_t)BATCH * SEQ * DOUT);  // 32768 shorts
    float* acc0    = (float*)(Sp + 32768);                         // 600
    float* acc1    = acc0 + 640;                                   // 600
    float* part    = acc1 + 640;                                   // 2048 * PSTR

    k_presplit<<<64, 256, 0, stream>>>(S_matrix, Sp);
    k_gemm<<<(BATCH * SEQ) / 128, 256, 0, stream>>>(low_capsule, Sp, lowp);

    k_iter<<<2 * BATCH, 256, 0, stream>>>(lowp, B_matrix, seq_len, acc0, acc1, part, out, 0);
    k_reduce<<<150, 256, 0, stream>>>(part, acc0);
    k_iter<<<2 * BATCH, 256, 0, stream>>>(lowp, B_matrix, seq_len, acc0, acc1, part, out, 1);
    k_reduce<<<150, 256, 0, stream>>>(part, acc1);
    k_iter<<<2 * BATCH, 256, 0, stream>>>(lowp, B_matrix, seq_len, acc0, acc1, part, out, 2);
}